// Round 17
// baseline (105.442 us; speedup 1.0000x reference)
//
#include <hip/hip_runtime.h>
#include <math.h>

#define S_LEN   2048
#define D_MODEL 768
#define NH      12
#define DH      64
#define BATCH   2

typedef __attribute__((ext_vector_type(4)))  float f32x4;
typedef __attribute__((ext_vector_type(16))) float f32x16;
typedef __attribute__((ext_vector_type(8)))  short bf16x8;
typedef __attribute__((ext_vector_type(4)))  short short4v;

__device__ __forceinline__ short f2bf(float f) {
    union { float f; unsigned u; } v; v.f = f;
    unsigned r = (v.u + 0x7FFFu + ((v.u >> 16) & 1u)) >> 16;
    return (short)r;
}
__device__ __forceinline__ float bf2f(short s) {
    union { unsigned u; float f; } v; v.u = ((unsigned)(unsigned short)s) << 16;
    return v.f;
}
__device__ __forceinline__ unsigned cvt_pk_bf16(float lo, float hi) {
    unsigned r;
    asm("v_cvt_pk_bf16_f32 %0, %1, %2" : "=v"(r) : "v"(lo), "v"(hi));
    return r;
}
__device__ __forceinline__ void perm32swap(unsigned &a, unsigned &b) {
    asm("v_permlane32_swap_b32 %0, %1" : "+v"(a), "+v"(b));
}
// v_exp_f32 computes 2^x — log2e folded into the Q scale upstream
__device__ __forceinline__ float exp2_fast(float x) {
    float r;
    asm("v_exp_f32 %0, %1" : "=v"(r) : "v"(x));
    return r;
}

#define GLOAD_LDS16(gp, lp)                                                     \
    __builtin_amdgcn_global_load_lds(                                           \
        (const __attribute__((address_space(1))) void*)(gp),                    \
        (__attribute__((address_space(3))) void*)(lp), 16, 0, 0)

// ---------------------------------------------------------------------------
// merged converts: blocks [0,4608) convert x fp32->bf16; [4608,5184) do W^T.
// ---------------------------------------------------------------------------
__global__ __launch_bounds__(256) void convert_xw_kernel(
    const float* __restrict__ x, short* __restrict__ xb,
    const float* __restrict__ wq, const float* __restrict__ wk,
    const float* __restrict__ wv, const float* __restrict__ wc,
    short* __restrict__ wt)
{
    const int bid = blockIdx.x;
    const int t = threadIdx.x;
    if (bid < 4608) {
        const size_t i = ((size_t)bid * 256 + t) * 8;
        const f32x4 a = *(const f32x4*)(x + i);
        const f32x4 b = *(const f32x4*)(x + i + 4);
        bf16x8 r;
        r[0] = f2bf(a[0]); r[1] = f2bf(a[1]); r[2] = f2bf(a[2]); r[3] = f2bf(a[3]);
        r[4] = f2bf(b[0]); r[5] = f2bf(b[1]); r[6] = f2bf(b[2]); r[7] = f2bf(b[3]);
        *(bf16x8*)(xb + i) = r;
        return;
    }
    __shared__ float Ld[64][65];
    const int rem = bid - 4608;
    const int z  = rem / 144;
    const int yy = (rem % 144) / 12;
    const int xx = rem % 12;
    const float* W = (z == 0) ? wq : (z == 1) ? wk : (z == 2) ? wv : wc;
    short* dst = wt + (size_t)z * D_MODEL * D_MODEL;
    const int r0 = yy * 64;
    const int c0 = xx * 64;

#pragma unroll
    for (int i = 0; i < 4; ++i) {
        const int r = (t >> 4) + 16 * i;
        const int c = (t & 15) * 4;
        const float4 a = *(const float4*)(W + (size_t)(r0 + r) * D_MODEL + c0 + c);
        Ld[r][c + 0] = a.x; Ld[r][c + 1] = a.y; Ld[r][c + 2] = a.z; Ld[r][c + 3] = a.w;
    }
    __syncthreads();
#pragma unroll
    for (int i = 0; i < 4; ++i) {
        const int n = (t >> 4) + 16 * i;
        const int kq = (t & 15) * 4;
        short4v s4;
        s4[0] = f2bf(Ld[kq + 0][n]); s4[1] = f2bf(Ld[kq + 1][n]);
        s4[2] = f2bf(Ld[kq + 2][n]); s4[3] = f2bf(Ld[kq + 3][n]);
        *(short4v*)(dst + (size_t)(c0 + n) * D_MODEL + r0 + kq) = s4;
    }
}

// ---------------------------------------------------------------------------
// bf16 MFMA GEMM (m97 structure) + XCD swizzle, templated on BM (128 or 64).
// BN fixed 128. out_mode: 0 fp32 row-major, 1 bf16 row-major, 2 Vt[bh][dh][s].
// ---------------------------------------------------------------------------
template <int BM>
__device__ __forceinline__ void gemm_bt_body(
    const short* __restrict__ A, int lda,
    const short* __restrict__ Bt,
    const float* __restrict__ bias,
    void* __restrict__ C, int ldc, int out_mode)
{
    __shared__ __align__(16) char ldsA[BM * 128];
    __shared__ __align__(16) char ldsB[16384];

    const int t = threadIdx.x, lane = t & 63, w = t >> 6;
    const int l15 = lane & 15, l4 = lane >> 4;
    const int wr = w >> 1, wc = w & 1;
    constexpr int RB = BM / 32;          // per-wave 16-row frags (4 or 2)

    // XCD swizzle (bijective: all grids have nwg % 8 == 0)
    const int l  = (int)blockIdx.x + (int)gridDim.x * (int)blockIdx.y;
    const int q8 = ((int)gridDim.x * (int)gridDim.y) >> 3;
    const int ls = (l & 7) * q8 + (l >> 3);
    const int row0 = (ls / (int)gridDim.x) * BM;
    const int col0 = (ls % (int)gridDim.x) * 128;

    const int srow = lane >> 3;
    const int sblk = (lane & 7) ^ srow;

    f32x4 acc[RB][4];
#pragma unroll
    for (int i = 0; i < RB; ++i)
#pragma unroll
        for (int j = 0; j < 4; ++j) acc[i][j] = (f32x4){0.f, 0.f, 0.f, 0.f};

    for (int kt = 0; kt < 12; ++kt) {
        __syncthreads();
#pragma unroll
        for (int i = 0; i < RB; ++i) {
            const int row = i * 32 + w * 8 + srow;
            GLOAD_LDS16(A + (size_t)(row0 + row) * lda + kt * 64 + sblk * 8,
                        ldsA + i * 4096 + w * 1024);
        }
#pragma unroll
        for (int i = 0; i < 4; ++i) {
            const int row = i * 32 + w * 8 + srow;
            GLOAD_LDS16(Bt + (size_t)(col0 + row) * D_MODEL + kt * 64 + sblk * 8,
                        ldsB + i * 4096 + w * 1024);
        }
        __syncthreads();

        bf16x8 af[RB][2], bfr[4][2];
#pragma unroll
        for (int rb = 0; rb < RB; ++rb) {
            const int r = wr * (BM / 2) + rb * 16 + l15;
#pragma unroll
            for (int c = 0; c < 2; ++c)
                af[rb][c] = *(const bf16x8*)(ldsA + r * 128 + (((c * 4 + l4) ^ (r & 7)) << 4));
        }
#pragma unroll
        for (int cb = 0; cb < 4; ++cb) {
            const int r = wc * 64 + cb * 16 + l15;
#pragma unroll
            for (int c = 0; c < 2; ++c)
                bfr[cb][c] = *(const bf16x8*)(ldsB + r * 128 + (((c * 4 + l4) ^ (r & 7)) << 4));
        }
        __builtin_amdgcn_s_setprio(1);
#pragma unroll
        for (int rb = 0; rb < RB; ++rb)
#pragma unroll
            for (int cb = 0; cb < 4; ++cb) {
                acc[rb][cb] = __builtin_amdgcn_mfma_f32_16x16x32_bf16(
                    af[rb][0], bfr[cb][0], acc[rb][cb], 0, 0, 0);
                acc[rb][cb] = __builtin_amdgcn_mfma_f32_16x16x32_bf16(
                    af[rb][1], bfr[cb][1], acc[rb][cb], 0, 0, 0);
            }
        __builtin_amdgcn_s_setprio(0);
    }

#pragma unroll
    for (int cb = 0; cb < 4; ++cb) {
        const int col = col0 + wc * 64 + cb * 16 + l15;
        const float bv = bias[col];
        if (out_mode == 2) {
            const int h  = col >> 6, dh = col & 63;
#pragma unroll
            for (int rb = 0; rb < RB; ++rb) {
                const int row = row0 + wr * (BM / 2) + rb * 16 + 4 * l4;
                const int b   = row >> 11, s0 = row & 2047;
                short4v s4;
                s4[0] = f2bf(acc[rb][cb][0] + bv);
                s4[1] = f2bf(acc[rb][cb][1] + bv);
                s4[2] = f2bf(acc[rb][cb][2] + bv);
                s4[3] = f2bf(acc[rb][cb][3] + bv);
                *(short4v*)((short*)C + ((size_t)((b * 12 + h) * 64 + dh)) * S_LEN + s0) = s4;
            }
        } else {
#pragma unroll
            for (int rb = 0; rb < RB; ++rb)
#pragma unroll
                for (int r = 0; r < 4; ++r) {
                    const int row = row0 + wr * (BM / 2) + rb * 16 + 4 * l4 + r;
                    const float val = acc[rb][cb][r] + bv;
                    if (out_mode == 1) ((short*)C)[(size_t)row * ldc + col] = f2bf(val);
                    else               ((float*)C)[(size_t)row * ldc + col] = val;
                }
        }
    }
}

// qkv: BM=64 -> grid (6,64,3) = 1152 blocks
__global__ __launch_bounds__(256) void qkv_gemm_kernel(
    const short* __restrict__ xb, const short* __restrict__ wt,
    const float* __restrict__ bq, const float* __restrict__ bk,
    const float* __restrict__ bv, short* __restrict__ qkv)
{
    const int which = blockIdx.z;
    const float* bias = (which == 0) ? bq : (which == 1) ? bk : bv;
    gemm_bt_body<64>(xb + which * D_MODEL, 3 * D_MODEL,
                     wt + (size_t)which * D_MODEL * D_MODEL, bias,
                     qkv + (size_t)which * BATCH * S_LEN * D_MODEL, D_MODEL,
                     (which == 2) ? 2 : 1);
}

// proj: BM=64 -> grid (6,64)=384 blocks
__global__ __launch_bounds__(256) void proj_gemm_kernel(
    const short* __restrict__ att, const short* __restrict__ wct,
    const float* __restrict__ bc, float* __restrict__ out)
{
    gemm_bt_body<64>(att, D_MODEL, wct, bc, out, D_MODEL, 0);
}

// ---------------------------------------------------------------------------
// Flash attention v10: QBLK=64, 4 waves = 2 q-waves x 2 KV-groups, grid
// (32,12,2)=768 blocks, 2 blocks/CU. R10's schedule UNCHANGED (full K+V
// double-buffer, issue-next-then-compute, 1 barrier/iter); only the grain
// halves: barrier domain 4 waves, uneven group split guarded via nld
// (R9's verified pattern). Staging: 4 gload_lds issues/wave.
// ---------------------------------------------------------------------------
__global__ __launch_bounds__(256, 2) void attn_mfma_kernel(
    const short* __restrict__ q, const short* __restrict__ k,
    const short* __restrict__ vt, short* __restrict__ o)
{
    __shared__ __align__(16) char bufK[2][2][8192];   // [group][dbuf]
    __shared__ __align__(16) char bufV[2][2][8192];
    __shared__ float mlx[2][64];

    const int t    = threadIdx.x;
    const int lane = t & 63;
    const int w    = t >> 6;        // 0..3
    const int g    = w >> 1;        // KV group
    const int w2   = w & 1;         // q-wave within group
    const int l31  = lane & 31;
    const int hi   = lane >> 5;
    const int r7   = l31 & 7;

    const int h  = blockIdx.y;
    const int b  = blockIdx.z;
    const int bh = h + 12 * b;
    const int qb = (bh >= 16) ? (31 - (int)blockIdx.x) : (int)blockIdx.x;
    const int nkt = qb + 1;
    const int cpg = (nkt + 1) >> 1;
    const int t0  = g * cpg;
    int nld = nkt - t0; if (nld > cpg) nld = cpg; if (nld < 0) nld = 0;

    const size_t base   = (size_t)b * (S_LEN * D_MODEL) + h * DH;
    const size_t vtbase = (size_t)bh * DH * S_LEN;
    const int q0 = qb * 64 + w2 * 32;

    // ---- Q B-frags; scale = 0.125*log2e folded in (exp2-space softmax) ----
    bf16x8 qf[4];
    {
        const float qscale = 0.18033688f;
        const short* qp = q + base + (size_t)(q0 + l31) * D_MODEL + 8 * hi;
#pragma unroll
        for (int dc = 0; dc < 4; ++dc) {
            bf16x8 r = *(const bf16x8*)(qp + 16 * dc);
#pragma unroll
            for (int j = 0; j < 8; ++j) r[j] = f2bf(bf2f(r[j]) * qscale);
            qf[dc] = r;
        }
    }

    f32x16 oT[2];
    oT[0] = (f32x16)(0.f); oT[1] = (f32x16)(0.f);
    float mrun = -1e30f, lrun = 0.f;

    const int srow = lane >> 3;
    const int sblk = (lane & 7) ^ srow;

    // ---- prologue: stage this group's tile 0 (4 issues/wave) ----
    if (nld > 0) {
#pragma unroll
        for (int j = 0; j < 4; ++j) {
            const int row = j * 16 + w2 * 8 + srow;
            GLOAD_LDS16(k  + base   + (size_t)(t0 * 64 + row) * D_MODEL + sblk * 8,
                        bufK[g][0] + j * 2048 + w2 * 1024);
            GLOAD_LDS16(vt + vtbase + (size_t)row * S_LEN + t0 * 64 + sblk * 8,
                        bufV[g][0] + j * 2048 + w2 * 1024);
        }
    }
    __syncthreads();

    for (int i = 0; i < cpg; ++i) {
        const int cur = i & 1, nxt = cur ^ 1;
        const int tk = t0 + i;

        // ---- issue next-tile loads first (hide HBM under compute) ----
        if (i + 1 < nld) {
            const int tkn = tk + 1;
#pragma unroll
            for (int j = 0; j < 4; ++j) {
                const int row = j * 16 + w2 * 8 + srow;
                GLOAD_LDS16(k  + base   + (size_t)(tkn * 64 + row) * D_MODEL + sblk * 8,
                            bufK[g][nxt] + (size_t)(j * 2048 + w2 * 1024));
                GLOAD_LDS16(vt + vtbase + (size_t)row * S_LEN + tkn * 64 + sblk * 8,
                            bufV[g][nxt] + (size_t)(j * 2048 + w2 * 1024));
            }
        }

        // ---- compute tile tk (wave-uniform causal skip) ----
        if (i < nld && tk * 64 <= q0 + 31) {
            f32x16 cS[2];
            __builtin_amdgcn_s_setprio(1);
#pragma unroll
            for (int s = 0; s < 2; ++s) {
                f32x16 acc = (f32x16)(0.f);
#pragma unroll
                for (int dc = 0; dc < 4; ++dc) {
                    const int row = 32 * s + l31;
                    const bf16x8 kf = *(const bf16x8*)(
                        bufK[g][cur] + row * 128 + (((unsigned)(32 * dc + 16 * hi)) ^ ((unsigned)r7 << 4)));
                    acc = __builtin_amdgcn_mfma_f32_32x32x16_bf16(kf, qf[dc], acc, 0, 0, 0);
                }
                cS[s] = acc;
            }
            __builtin_amdgcn_s_setprio(0);

            if (tk * 64 + 63 > q0) {   // boundary tiles: causal mask
                const int qg = q0 + l31;
#pragma unroll
                for (int s = 0; s < 2; ++s)
#pragma unroll
                    for (int rg = 0; rg < 16; ++rg) {
                        const int key = tk * 64 + 32 * s + (rg & 3) + 8 * (rg >> 2) + 4 * hi;
                        if (key > qg) cS[s][rg] = -1e30f;
                    }
            }

            // online softmax in exp2 space, defer-max (THR = 8*log2e = 11.52)
            float pmax = -1e30f;
#pragma unroll
            for (int s = 0; s < 2; ++s)
#pragma unroll
                for (int rg = 0; rg < 16; ++rg) pmax = fmaxf(pmax, cS[s][rg]);
            pmax = fmaxf(pmax, __shfl_xor(pmax, 32));

            if (!__all(pmax - mrun <= 11.52f)) {
                const float mnew = fmaxf(mrun, pmax);
                const float corr = exp2_fast(mrun - mnew);
                lrun *= corr;
#pragma unroll
                for (int d0 = 0; d0 < 2; ++d0)
#pragma unroll
                    for (int rg = 0; rg < 16; ++rg) oT[d0][rg] *= corr;
                mrun = mnew;
            }
            float psum = 0.f;
#pragma unroll
            for (int s = 0; s < 2; ++s)
#pragma unroll
                for (int rg = 0; rg < 16; ++rg) {
                    const float e = exp2_fast(cS[s][rg] - mrun);
                    cS[s][rg] = e; psum += e;
                }
            psum += __shfl_xor(psum, 32);
            lrun += psum;

            // P -> bf16 B-frags in-register
            bf16x8 pfrag[4];
#pragma unroll
            for (int s = 0; s < 2; ++s)
#pragma unroll
                for (int tt = 0; tt < 2; ++tt) {
                    unsigned a0 = cvt_pk_bf16(cS[s][8 * tt + 0], cS[s][8 * tt + 1]);
                    unsigned a1 = cvt_pk_bf16(cS[s][8 * tt + 2], cS[s][8 * tt + 3]);
                    unsigned b0 = cvt_pk_bf16(cS[s][8 * tt + 4], cS[s][8 * tt + 5]);
                    unsigned b1 = cvt_pk_bf16(cS[s][8 * tt + 6], cS[s][8 * tt + 7]);
                    perm32swap(a0, b0);
                    perm32swap(a1, b1);
                    union { unsigned u[4]; bf16x8 v8; } pk;
                    pk.u[0] = a0; pk.u[1] = a1; pk.u[2] = b0; pk.u[3] = b1;
                    pfrag[2 * s + tt] = pk.v8;
                }

            // O^T += Vt . P
            __builtin_amdgcn_s_setprio(1);
#pragma unroll
            for (int d0 = 0; d0 < 2; ++d0) {
                f32x16 acc = oT[d0];
#pragma unroll
                for (int c = 0; c < 4; ++c) {
                    const int row = 32 * d0 + l31;
                    const bf16x8 vf = *(const bf16x8*)(
                        bufV[g][cur] + row * 128 + (((unsigned)(32 * c + 16 * hi)) ^ ((unsigned)r7 << 4)));
                    acc = __builtin_amdgcn_mfma_f32_32x32x16_bf16(vf, pfrag[c], acc, 0, 0, 0);
                }
                oT[d0] = acc;
            }
            __builtin_amdgcn_s_setprio(0);
        }
        __syncthreads();
    }

    // ---- group 1 publishes unnormalized partials into dead bufK LDS ----
    if (g == 1) {
        float* ex = (float*)(&bufK[0][0][0]) + w2 * 2048;
#pragma unroll
        for (int d0 = 0; d0 < 2; ++d0)
#pragma unroll
            for (int rg = 0; rg < 16; ++rg)
                ex[(d0 * 16 + rg) * 64 + lane] = oT[d0][rg];
        if (hi == 0) {
            mlx[0][w2 * 32 + l31] = mrun;
            mlx[1][w2 * 32 + l31] = lrun;
        }
    }
    __syncthreads();

    // ---- group 0: flash-decode combine + DIRECT global store ----
    if (g == 0) {
        const int row = w2 * 32 + l31;
        const float m1  = mlx[0][row];
        const float l1v = mlx[1][row];
        const float M   = fmaxf(mrun, m1);
        const float a0  = exp2_fast(mrun - M);
        const float a1  = exp2_fast(m1 - M);
        const float inv = 1.f / (a0 * lrun + a1 * l1v);
        const float c0  = a0 * inv;
        const float c1  = a1 * inv;
        const float* ex = (const float*)(&bufK[0][0][0]) + w2 * 2048;

        short* orow = o + base + (size_t)(qb * 64 + row) * D_MODEL;
#pragma unroll
        for (int d0 = 0; d0 < 2; ++d0)
#pragma unroll
            for (int gg = 0; gg < 4; ++gg) {
                short4v s4;
#pragma unroll
                for (int j = 0; j < 4; ++j) {
                    const int rg = 4 * gg + j;
                    const float val = c0 * oT[d0][rg] + c1 * ex[(d0 * 16 + rg) * 64 + lane];
                    s4[j] = f2bf(val);
                }
                *(short4v*)(orow + 32 * d0 + 8 * gg + 4 * hi) = s4;
            }
    }
}

extern "C" void kernel_launch(void* const* d_in, const int* in_sizes, int n_in,
                              void* d_out, int out_size, void* d_ws, size_t ws_size,
                              hipStream_t stream)
{
    const float* x  = (const float*)d_in[0];
    // d_in[1] = mask: exact causal triu -> analytic, not read
    const float* wq = (const float*)d_in[2];
    const float* bq = (const float*)d_in[3];
    const float* wk = (const float*)d_in[4];
    const float* bk = (const float*)d_in[5];
    const float* wv = (const float*)d_in[6];
    const float* bv = (const float*)d_in[7];
    const float* wc = (const float*)d_in[8];
    const float* bc = (const float*)d_in[9];
    float* out = (float*)d_out;

    const size_t nx  = (size_t)BATCH * S_LEN * 3 * D_MODEL;
    const size_t nw  = (size_t)D_MODEL * D_MODEL;
    const size_t nqv = (size_t)BATCH * S_LEN * D_MODEL;

    short* xb  = (short*)d_ws;
    short* wt  = xb + nx;
    short* qkv = wt + 4 * nw;        // q | k | Vt (Vt transposed per head)
    short* att = qkv + 3 * nqv;

    dim3 blk(256);
    convert_xw_kernel<<<dim3(4608 + 576), blk, 0, stream>>>(x, xb, wq, wk, wv, wc, wt);
    qkv_gemm_kernel  <<<dim3(6, 64, 3), blk, 0, stream>>>(xb, wt, bq, bk, bv, qkv);
    attn_mfma_kernel <<<dim3(32, NH, BATCH), blk, 0, stream>>>(
        qkv, qkv + nqv, qkv + 2 * nqv, att);
    proj_gemm_kernel <<<dim3(6, 64), blk, 0, stream>>>(att, wt + 3 * nw, bc, out);
}

// Round 18
// 99.937 us; speedup vs baseline: 1.0551x; 1.0551x over previous
//
#include <hip/hip_runtime.h>
#include <math.h>

#define S_LEN   2048
#define D_MODEL 768
#define NH      12
#define DH      64
#define BATCH   2

typedef __attribute__((ext_vector_type(4)))  float f32x4;
typedef __attribute__((ext_vector_type(16))) float f32x16;
typedef __attribute__((ext_vector_type(8)))  short bf16x8;
typedef __attribute__((ext_vector_type(4)))  short short4v;

__device__ __forceinline__ short f2bf(float f) {
    union { float f; unsigned u; } v; v.f = f;
    unsigned r = (v.u + 0x7FFFu + ((v.u >> 16) & 1u)) >> 16;
    return (short)r;
}
__device__ __forceinline__ float bf2f(short s) {
    union { unsigned u; float f; } v; v.u = ((unsigned)(unsigned short)s) << 16;
    return v.f;
}
__device__ __forceinline__ unsigned cvt_pk_bf16(float lo, float hi) {
    unsigned r;
    asm("v_cvt_pk_bf16_f32 %0, %1, %2" : "=v"(r) : "v"(lo), "v"(hi));
    return r;
}
__device__ __forceinline__ void perm32swap(unsigned &a, unsigned &b) {
    asm("v_permlane32_swap_b32 %0, %1" : "+v"(a), "+v"(b));
}
// v_exp_f32 computes 2^x — log2e folded into the Q scale upstream
__device__ __forceinline__ float exp2_fast(float x) {
    float r;
    asm("v_exp_f32 %0, %1" : "=v"(r) : "v"(x));
    return r;
}

#define GLOAD_LDS16(gp, lp)                                                     \
    __builtin_amdgcn_global_load_lds(                                           \
        (const __attribute__((address_space(1))) void*)(gp),                    \
        (__attribute__((address_space(3))) void*)(lp), 16, 0, 0)

// ---------------------------------------------------------------------------
// merged converts: blocks [0,4608) convert x fp32->bf16; [4608,5184) do W^T.
// ---------------------------------------------------------------------------
__global__ __launch_bounds__(256) void convert_xw_kernel(
    const float* __restrict__ x, short* __restrict__ xb,
    const float* __restrict__ wq, const float* __restrict__ wk,
    const float* __restrict__ wv, const float* __restrict__ wc,
    short* __restrict__ wt)
{
    const int bid = blockIdx.x;
    const int t = threadIdx.x;
    if (bid < 4608) {
        const size_t i = ((size_t)bid * 256 + t) * 8;
        const f32x4 a = *(const f32x4*)(x + i);
        const f32x4 b = *(const f32x4*)(x + i + 4);
        bf16x8 r;
        r[0] = f2bf(a[0]); r[1] = f2bf(a[1]); r[2] = f2bf(a[2]); r[3] = f2bf(a[3]);
        r[4] = f2bf(b[0]); r[5] = f2bf(b[1]); r[6] = f2bf(b[2]); r[7] = f2bf(b[3]);
        *(bf16x8*)(xb + i) = r;
        return;
    }
    __shared__ float Ld[64][65];
    const int rem = bid - 4608;
    const int z  = rem / 144;
    const int yy = (rem % 144) / 12;
    const int xx = rem % 12;
    const float* W = (z == 0) ? wq : (z == 1) ? wk : (z == 2) ? wv : wc;
    short* dst = wt + (size_t)z * D_MODEL * D_MODEL;
    const int r0 = yy * 64;
    const int c0 = xx * 64;

#pragma unroll
    for (int i = 0; i < 4; ++i) {
        const int r = (t >> 4) + 16 * i;
        const int c = (t & 15) * 4;
        const float4 a = *(const float4*)(W + (size_t)(r0 + r) * D_MODEL + c0 + c);
        Ld[r][c + 0] = a.x; Ld[r][c + 1] = a.y; Ld[r][c + 2] = a.z; Ld[r][c + 3] = a.w;
    }
    __syncthreads();
#pragma unroll
    for (int i = 0; i < 4; ++i) {
        const int n = (t >> 4) + 16 * i;
        const int kq = (t & 15) * 4;
        short4v s4;
        s4[0] = f2bf(Ld[kq + 0][n]); s4[1] = f2bf(Ld[kq + 1][n]);
        s4[2] = f2bf(Ld[kq + 2][n]); s4[3] = f2bf(Ld[kq + 3][n]);
        *(short4v*)(dst + (size_t)(c0 + n) * D_MODEL + r0 + kq) = s4;
    }
}

// ---------------------------------------------------------------------------
// bf16 MFMA GEMM (m97 structure) + XCD swizzle, templated on BM (128 or 64).
// BN fixed 128. out_mode: 0 fp32 row-major, 1 bf16 row-major, 2 Vt[bh][dh][s].
// ---------------------------------------------------------------------------
template <int BM>
__device__ __forceinline__ void gemm_bt_body(
    const short* __restrict__ A, int lda,
    const short* __restrict__ Bt,
    const float* __restrict__ bias,
    void* __restrict__ C, int ldc, int out_mode)
{
    __shared__ __align__(16) char ldsA[BM * 128];
    __shared__ __align__(16) char ldsB[16384];

    const int t = threadIdx.x, lane = t & 63, w = t >> 6;
    const int l15 = lane & 15, l4 = lane >> 4;
    const int wr = w >> 1, wc = w & 1;
    constexpr int RB = BM / 32;          // per-wave 16-row frags (4 or 2)

    // XCD swizzle (bijective: all grids have nwg % 8 == 0)
    const int l  = (int)blockIdx.x + (int)gridDim.x * (int)blockIdx.y;
    const int q8 = ((int)gridDim.x * (int)gridDim.y) >> 3;
    const int ls = (l & 7) * q8 + (l >> 3);
    const int row0 = (ls / (int)gridDim.x) * BM;
    const int col0 = (ls % (int)gridDim.x) * 128;

    const int srow = lane >> 3;
    const int sblk = (lane & 7) ^ srow;

    f32x4 acc[RB][4];
#pragma unroll
    for (int i = 0; i < RB; ++i)
#pragma unroll
        for (int j = 0; j < 4; ++j) acc[i][j] = (f32x4){0.f, 0.f, 0.f, 0.f};

    for (int kt = 0; kt < 12; ++kt) {
        __syncthreads();
#pragma unroll
        for (int i = 0; i < RB; ++i) {
            const int row = i * 32 + w * 8 + srow;
            GLOAD_LDS16(A + (size_t)(row0 + row) * lda + kt * 64 + sblk * 8,
                        ldsA + i * 4096 + w * 1024);
        }
#pragma unroll
        for (int i = 0; i < 4; ++i) {
            const int row = i * 32 + w * 8 + srow;
            GLOAD_LDS16(Bt + (size_t)(col0 + row) * D_MODEL + kt * 64 + sblk * 8,
                        ldsB + i * 4096 + w * 1024);
        }
        __syncthreads();

        bf16x8 af[RB][2], bfr[4][2];
#pragma unroll
        for (int rb = 0; rb < RB; ++rb) {
            const int r = wr * (BM / 2) + rb * 16 + l15;
#pragma unroll
            for (int c = 0; c < 2; ++c)
                af[rb][c] = *(const bf16x8*)(ldsA + r * 128 + (((c * 4 + l4) ^ (r & 7)) << 4));
        }
#pragma unroll
        for (int cb = 0; cb < 4; ++cb) {
            const int r = wc * 64 + cb * 16 + l15;
#pragma unroll
            for (int c = 0; c < 2; ++c)
                bfr[cb][c] = *(const bf16x8*)(ldsB + r * 128 + (((c * 4 + l4) ^ (r & 7)) << 4));
        }
        __builtin_amdgcn_s_setprio(1);
#pragma unroll
        for (int rb = 0; rb < RB; ++rb)
#pragma unroll
            for (int cb = 0; cb < 4; ++cb) {
                acc[rb][cb] = __builtin_amdgcn_mfma_f32_16x16x32_bf16(
                    af[rb][0], bfr[cb][0], acc[rb][cb], 0, 0, 0);
                acc[rb][cb] = __builtin_amdgcn_mfma_f32_16x16x32_bf16(
                    af[rb][1], bfr[cb][1], acc[rb][cb], 0, 0, 0);
            }
        __builtin_amdgcn_s_setprio(0);
    }

#pragma unroll
    for (int cb = 0; cb < 4; ++cb) {
        const int col = col0 + wc * 64 + cb * 16 + l15;
        const float bv = bias[col];
        if (out_mode == 2) {
            const int h  = col >> 6, dh = col & 63;
#pragma unroll
            for (int rb = 0; rb < RB; ++rb) {
                const int row = row0 + wr * (BM / 2) + rb * 16 + 4 * l4;
                const int b   = row >> 11, s0 = row & 2047;
                short4v s4;
                s4[0] = f2bf(acc[rb][cb][0] + bv);
                s4[1] = f2bf(acc[rb][cb][1] + bv);
                s4[2] = f2bf(acc[rb][cb][2] + bv);
                s4[3] = f2bf(acc[rb][cb][3] + bv);
                *(short4v*)((short*)C + ((size_t)((b * 12 + h) * 64 + dh)) * S_LEN + s0) = s4;
            }
        } else {
#pragma unroll
            for (int rb = 0; rb < RB; ++rb)
#pragma unroll
                for (int r = 0; r < 4; ++r) {
                    const int row = row0 + wr * (BM / 2) + rb * 16 + 4 * l4 + r;
                    const float val = acc[rb][cb][r] + bv;
                    if (out_mode == 1) ((short*)C)[(size_t)row * ldc + col] = f2bf(val);
                    else               ((float*)C)[(size_t)row * ldc + col] = val;
                }
        }
    }
}

// qkv: BM=64 -> grid (6,64,3) = 1152 blocks
__global__ __launch_bounds__(256) void qkv_gemm_kernel(
    const short* __restrict__ xb, const short* __restrict__ wt,
    const float* __restrict__ bq, const float* __restrict__ bk,
    const float* __restrict__ bv, short* __restrict__ qkv)
{
    const int which = blockIdx.z;
    const float* bias = (which == 0) ? bq : (which == 1) ? bk : bv;
    gemm_bt_body<64>(xb + which * D_MODEL, 3 * D_MODEL,
                     wt + (size_t)which * D_MODEL * D_MODEL, bias,
                     qkv + (size_t)which * BATCH * S_LEN * D_MODEL, D_MODEL,
                     (which == 2) ? 2 : 1);
}

// proj: BM=64 -> grid (6,64)=384 blocks
__global__ __launch_bounds__(256) void proj_gemm_kernel(
    const short* __restrict__ att, const short* __restrict__ wct,
    const float* __restrict__ bc, float* __restrict__ out)
{
    gemm_bt_body<64>(att, D_MODEL, wct, bc, out, D_MODEL, 0);
}

// ---------------------------------------------------------------------------
// Flash attention v8 + XCD-grouped work map. Grid (16,12,2)=384, 512 thr.
// Linear id L -> XCD L%8; work w = (L%8)*48 + L/8; bh = w/16, qt = w%16.
// Each XCD owns 3 complete heads: all 16 q-blocks of a head share that
// XCD's L2 for K/V (768 KB << 4 MB), and per-XCD work is 3 full causal
// triangles (balanced). Schedule/math identical to R10/R12/R16.
// ---------------------------------------------------------------------------
__global__ __launch_bounds__(512, 4) void attn_mfma_kernel(
    const short* __restrict__ q, const short* __restrict__ k,
    const short* __restrict__ vt, short* __restrict__ o)
{
    __shared__ __align__(16) char bufK[2][2][8192];   // [group][dbuf]
    __shared__ __align__(16) char bufV[2][2][8192];
    __shared__ float mlx[2][128];

    const int t    = threadIdx.x;
    const int lane = t & 63;
    const int w    = t >> 6;
    const int g    = w >> 2;
    const int w4   = w & 3;
    const int l31  = lane & 31;
    const int hi   = lane >> 5;
    const int r7   = l31 & 7;

    // XCD-grouped work mapping (bijective, 384 = 8 * 48)
    const int L  = (int)blockIdx.x + 16 * ((int)blockIdx.y + 12 * (int)blockIdx.z);
    const int ww = (L & 7) * 48 + (L >> 3);
    const int bh = ww >> 4;               // 0..23
    const int qt = ww & 15;
    const int h  = bh % 12;
    const int b  = bh / 12;
    const int nt = qt + 1;

    const size_t base   = (size_t)b * (S_LEN * D_MODEL) + h * DH;
    const size_t vtbase = (size_t)bh * DH * S_LEN;
    const int q0 = qt * 128 + w4 * 32;

    // ---- Q B-frags; scale = 0.125*log2e folded in (exp2-space softmax) ----
    bf16x8 qf[4];
    {
        const float qscale = 0.18033688f;
        const short* qp = q + base + (size_t)(q0 + l31) * D_MODEL + 8 * hi;
#pragma unroll
        for (int dc = 0; dc < 4; ++dc) {
            bf16x8 r = *(const bf16x8*)(qp + 16 * dc);
#pragma unroll
            for (int j = 0; j < 8; ++j) r[j] = f2bf(bf2f(r[j]) * qscale);
            qf[dc] = r;
        }
    }

    f32x16 oT[2];
    oT[0] = (f32x16)(0.f); oT[1] = (f32x16)(0.f);
    float mrun = -1e30f, lrun = 0.f;

    const int srow = lane >> 3;
    const int sblk = (lane & 7) ^ srow;

    // ---- prologue: stage this group's tile 0 ----
    {
        const int tk0 = g * nt;
#pragma unroll
        for (int i = 0; i < 2; ++i) {
            const int row = i * 32 + w4 * 8 + srow;
            GLOAD_LDS16(k  + base   + (size_t)(tk0 * 64 + row) * D_MODEL + sblk * 8,
                        bufK[g][0] + i * 4096 + w4 * 1024);
            GLOAD_LDS16(vt + vtbase + (size_t)row * S_LEN + tk0 * 64 + sblk * 8,
                        bufV[g][0] + i * 4096 + w4 * 1024);
        }
        __syncthreads();
    }

    for (int i = 0; i < nt; ++i) {
        const int cur = i & 1, nxt = cur ^ 1;
        const bool have_next = (i + 1 < nt);
        const int tk = g * nt + i;

        // ---- issue next-tile loads first (hide HBM under compute) ----
        if (have_next) {
            const int tkn = tk + 1;
#pragma unroll
            for (int j = 0; j < 2; ++j) {
                const int row = j * 32 + w4 * 8 + srow;
                GLOAD_LDS16(k  + base   + (size_t)(tkn * 64 + row) * D_MODEL + sblk * 8,
                            bufK[g][nxt] + (size_t)(j * 4096 + w4 * 1024));
                GLOAD_LDS16(vt + vtbase + (size_t)row * S_LEN + tkn * 64 + sblk * 8,
                            bufV[g][nxt] + (size_t)(j * 4096 + w4 * 1024));
            }
        }

        // ---- compute tile tk (wave-uniform causal skip) ----
        if (tk * 64 <= q0 + 31) {
            f32x16 cS[2];
            __builtin_amdgcn_s_setprio(1);
#pragma unroll
            for (int s = 0; s < 2; ++s) {
                f32x16 acc = (f32x16)(0.f);
#pragma unroll
                for (int dc = 0; dc < 4; ++dc) {
                    const int row = 32 * s + l31;
                    const bf16x8 kf = *(const bf16x8*)(
                        bufK[g][cur] + row * 128 + (((unsigned)(32 * dc + 16 * hi)) ^ ((unsigned)r7 << 4)));
                    acc = __builtin_amdgcn_mfma_f32_32x32x16_bf16(kf, qf[dc], acc, 0, 0, 0);
                }
                cS[s] = acc;
            }
            __builtin_amdgcn_s_setprio(0);

            if (tk * 64 + 63 > q0) {   // boundary tiles: causal mask
                const int qg = q0 + l31;
#pragma unroll
                for (int s = 0; s < 2; ++s)
#pragma unroll
                    for (int rg = 0; rg < 16; ++rg) {
                        const int key = tk * 64 + 32 * s + (rg & 3) + 8 * (rg >> 2) + 4 * hi;
                        if (key > qg) cS[s][rg] = -1e30f;
                    }
            }

            // online softmax in exp2 space, defer-max (THR = 8*log2e = 11.52)
            float pmax = -1e30f;
#pragma unroll
            for (int s = 0; s < 2; ++s)
#pragma unroll
                for (int rg = 0; rg < 16; ++rg) pmax = fmaxf(pmax, cS[s][rg]);
            pmax = fmaxf(pmax, __shfl_xor(pmax, 32));

            if (!__all(pmax - mrun <= 11.52f)) {
                const float mnew = fmaxf(mrun, pmax);
                const float corr = exp2_fast(mrun - mnew);
                lrun *= corr;
#pragma unroll
                for (int d0 = 0; d0 < 2; ++d0)
#pragma unroll
                    for (int rg = 0; rg < 16; ++rg) oT[d0][rg] *= corr;
                mrun = mnew;
            }
            float psum = 0.f;
#pragma unroll
            for (int s = 0; s < 2; ++s)
#pragma unroll
                for (int rg = 0; rg < 16; ++rg) {
                    const float e = exp2_fast(cS[s][rg] - mrun);
                    cS[s][rg] = e; psum += e;
                }
            psum += __shfl_xor(psum, 32);
            lrun += psum;

            // P -> bf16 B-frags in-register
            bf16x8 pfrag[4];
#pragma unroll
            for (int s = 0; s < 2; ++s)
#pragma unroll
                for (int tt = 0; tt < 2; ++tt) {
                    unsigned a0 = cvt_pk_bf16(cS[s][8 * tt + 0], cS[s][8 * tt + 1]);
                    unsigned a1 = cvt_pk_bf16(cS[s][8 * tt + 2], cS[s][8 * tt + 3]);
                    unsigned b0 = cvt_pk_bf16(cS[s][8 * tt + 4], cS[s][8 * tt + 5]);
                    unsigned b1 = cvt_pk_bf16(cS[s][8 * tt + 6], cS[s][8 * tt + 7]);
                    perm32swap(a0, b0);
                    perm32swap(a1, b1);
                    union { unsigned u[4]; bf16x8 v8; } pk;
                    pk.u[0] = a0; pk.u[1] = a1; pk.u[2] = b0; pk.u[3] = b1;
                    pfrag[2 * s + tt] = pk.v8;
                }

            // O^T += Vt . P
            __builtin_amdgcn_s_setprio(1);
#pragma unroll
            for (int d0 = 0; d0 < 2; ++d0) {
                f32x16 acc = oT[d0];
#pragma unroll
                for (int c = 0; c < 4; ++c) {
                    const int row = 32 * d0 + l31;
                    const bf16x8 vf = *(const bf16x8*)(
                        bufV[g][cur] + row * 128 + (((unsigned)(32 * c + 16 * hi)) ^ ((unsigned)r7 << 4)));
                    acc = __builtin_amdgcn_mfma_f32_32x32x16_bf16(vf, pfrag[c], acc, 0, 0, 0);
                }
                oT[d0] = acc;
            }
            __builtin_amdgcn_s_setprio(0);
        }
        __syncthreads();
    }

    // ---- group 1 publishes unnormalized partials into dead bufK LDS ----
    if (g == 1) {
        float* ex = (float*)(&bufK[0][0][0]) + w4 * 2048;
#pragma unroll
        for (int d0 = 0; d0 < 2; ++d0)
#pragma unroll
            for (int rg = 0; rg < 16; ++rg)
                ex[(d0 * 16 + rg) * 64 + lane] = oT[d0][rg];
        if (hi == 0) {
            mlx[0][w4 * 32 + l31] = mrun;
            mlx[1][w4 * 32 + l31] = lrun;
        }
    }
    __syncthreads();

    // ---- group 0: flash-decode combine + DIRECT global store ----
    if (g == 0) {
        const int row = w4 * 32 + l31;
        const float m1  = mlx[0][row];
        const float l1v = mlx[1][row];
        const float M   = fmaxf(mrun, m1);
        const float a0  = exp2_fast(mrun - M);
        const float a1  = exp2_fast(m1 - M);
        const float inv = 1.f / (a0 * lrun + a1 * l1v);
        const float c0  = a0 * inv;
        const float c1  = a1 * inv;
        const float* ex = (const float*)(&bufK[0][0][0]) + w4 * 2048;

        short* orow = o + base + (size_t)(qt * 128 + row) * D_MODEL;
#pragma unroll
        for (int d0 = 0; d0 < 2; ++d0)
#pragma unroll
            for (int gg = 0; gg < 4; ++gg) {
                short4v s4;
#pragma unroll
                for (int j = 0; j < 4; ++j) {
                    const int rg = 4 * gg + j;
                    const float val = c0 * oT[d0][rg] + c1 * ex[(d0 * 16 + rg) * 64 + lane];
                    s4[j] = f2bf(val);
                }
                *(short4v*)(orow + 32 * d0 + 8 * gg + 4 * hi) = s4;
            }
    }
}

extern "C" void kernel_launch(void* const* d_in, const int* in_sizes, int n_in,
                              void* d_out, int out_size, void* d_ws, size_t ws_size,
                              hipStream_t stream)
{
    const float* x  = (const float*)d_in[0];
    // d_in[1] = mask: exact causal triu -> analytic, not read
    const float* wq = (const float*)d_in[2];
    const float* bq = (const float*)d_in[3];
    const float* wk = (const float*)d_in[4];
    const float* bk = (const float*)d_in[5];
    const float* wv = (const float*)d_in[6];
    const float* bv = (const float*)d_in[7];
    const float* wc = (const float*)d_in[8];
    const float* bc = (const float*)d_in[9];
    float* out = (float*)d_out;

    const size_t nx  = (size_t)BATCH * S_LEN * 3 * D_MODEL;
    const size_t nw  = (size_t)D_MODEL * D_MODEL;
    const size_t nqv = (size_t)BATCH * S_LEN * D_MODEL;

    short* xb  = (short*)d_ws;
    short* wt  = xb + nx;
    short* qkv = wt + 4 * nw;        // q | k | Vt (Vt transposed per head)
    short* att = qkv + 3 * nqv;

    dim3 blk(256);
    convert_xw_kernel<<<dim3(4608 + 576), blk, 0, stream>>>(x, xb, wq, wk, wv, wc, wt);
    qkv_gemm_kernel  <<<dim3(6, 64, 3), blk, 0, stream>>>(xb, wt, bq, bk, bv, qkv);
    attn_mfma_kernel <<<dim3(16, NH, BATCH), dim3(512), 0, stream>>>(
        qkv, qkv + nqv, qkv + 2 * nqv, att);
    proj_gemm_kernel <<<dim3(6, 64), blk, 0, stream>>>(att, wt + 3 * nw, bc, out);
}

// Round 19
// 90.167 us; speedup vs baseline: 1.1694x; 1.1083x over previous
//
#include <hip/hip_runtime.h>
#include <math.h>

#define S_LEN   2048
#define D_MODEL 768
#define NH      12
#define DH      64
#define BATCH   2

typedef __attribute__((ext_vector_type(4)))  float f32x4;
typedef __attribute__((ext_vector_type(16))) float f32x16;
typedef __attribute__((ext_vector_type(8)))  short bf16x8;
typedef __attribute__((ext_vector_type(4)))  short short4v;

__device__ __forceinline__ short f2bf(float f) {
    union { float f; unsigned u; } v; v.f = f;
    unsigned r = (v.u + 0x7FFFu + ((v.u >> 16) & 1u)) >> 16;
    return (short)r;
}
__device__ __forceinline__ float bf2f(short s) {
    union { unsigned u; float f; } v; v.u = ((unsigned)(unsigned short)s) << 16;
    return v.f;
}
__device__ __forceinline__ unsigned cvt_pk_bf16(float lo, float hi) {
    unsigned r;
    asm("v_cvt_pk_bf16_f32 %0, %1, %2" : "=v"(r) : "v"(lo), "v"(hi));
    return r;
}
__device__ __forceinline__ void perm32swap(unsigned &a, unsigned &b) {
    asm("v_permlane32_swap_b32 %0, %1" : "+v"(a), "+v"(b));
}
// v_exp_f32 computes 2^x — log2e folded into the Q scale upstream
__device__ __forceinline__ float exp2_fast(float x) {
    float r;
    asm("v_exp_f32 %0, %1" : "=v"(r) : "v"(x));
    return r;
}

#define GLOAD_LDS16(gp, lp)                                                     \
    __builtin_amdgcn_global_load_lds(                                           \
        (const __attribute__((address_space(1))) void*)(gp),                    \
        (__attribute__((address_space(3))) void*)(lp), 16, 0, 0)

// ---------------------------------------------------------------------------
// merged converts: blocks [0,4608) convert x fp32->bf16; [4608,5184) do W^T.
// ---------------------------------------------------------------------------
__global__ __launch_bounds__(256) void convert_xw_kernel(
    const float* __restrict__ x, short* __restrict__ xb,
    const float* __restrict__ wq, const float* __restrict__ wk,
    const float* __restrict__ wv, const float* __restrict__ wc,
    short* __restrict__ wt)
{
    const int bid = blockIdx.x;
    const int t = threadIdx.x;
    if (bid < 4608) {
        const size_t i = ((size_t)bid * 256 + t) * 8;
        const f32x4 a = *(const f32x4*)(x + i);
        const f32x4 b = *(const f32x4*)(x + i + 4);
        bf16x8 r;
        r[0] = f2bf(a[0]); r[1] = f2bf(a[1]); r[2] = f2bf(a[2]); r[3] = f2bf(a[3]);
        r[4] = f2bf(b[0]); r[5] = f2bf(b[1]); r[6] = f2bf(b[2]); r[7] = f2bf(b[3]);
        *(bf16x8*)(xb + i) = r;
        return;
    }
    __shared__ float Ld[64][65];
    const int rem = bid - 4608;
    const int z  = rem / 144;
    const int yy = (rem % 144) / 12;
    const int xx = rem % 12;
    const float* W = (z == 0) ? wq : (z == 1) ? wk : (z == 2) ? wv : wc;
    short* dst = wt + (size_t)z * D_MODEL * D_MODEL;
    const int r0 = yy * 64;
    const int c0 = xx * 64;

#pragma unroll
    for (int i = 0; i < 4; ++i) {
        const int r = (t >> 4) + 16 * i;
        const int c = (t & 15) * 4;
        const float4 a = *(const float4*)(W + (size_t)(r0 + r) * D_MODEL + c0 + c);
        Ld[r][c + 0] = a.x; Ld[r][c + 1] = a.y; Ld[r][c + 2] = a.z; Ld[r][c + 3] = a.w;
    }
    __syncthreads();
#pragma unroll
    for (int i = 0; i < 4; ++i) {
        const int n = (t >> 4) + 16 * i;
        const int kq = (t & 15) * 4;
        short4v s4;
        s4[0] = f2bf(Ld[kq + 0][n]); s4[1] = f2bf(Ld[kq + 1][n]);
        s4[2] = f2bf(Ld[kq + 2][n]); s4[3] = f2bf(Ld[kq + 3][n]);
        *(short4v*)(dst + (size_t)(c0 + n) * D_MODEL + r0 + kq) = s4;
    }
}

// ---------------------------------------------------------------------------
// bf16 MFMA GEMM (m97 structure) + XCD swizzle, templated on BM (128 or 64).
// BN fixed 128. out_mode: 0 fp32 row-major, 1 bf16 row-major, 2 Vt[bh][dh][s].
// ---------------------------------------------------------------------------
template <int BM>
__device__ __forceinline__ void gemm_bt_body(
    const short* __restrict__ A, int lda,
    const short* __restrict__ Bt,
    const float* __restrict__ bias,
    void* __restrict__ C, int ldc, int out_mode)
{
    __shared__ __align__(16) char ldsA[BM * 128];
    __shared__ __align__(16) char ldsB[16384];

    const int t = threadIdx.x, lane = t & 63, w = t >> 6;
    const int l15 = lane & 15, l4 = lane >> 4;
    const int wr = w >> 1, wc = w & 1;
    constexpr int RB = BM / 32;          // per-wave 16-row frags (4 or 2)

    // XCD swizzle (bijective: all grids have nwg % 8 == 0)
    const int l  = (int)blockIdx.x + (int)gridDim.x * (int)blockIdx.y;
    const int q8 = ((int)gridDim.x * (int)gridDim.y) >> 3;
    const int ls = (l & 7) * q8 + (l >> 3);
    const int row0 = (ls / (int)gridDim.x) * BM;
    const int col0 = (ls % (int)gridDim.x) * 128;

    const int srow = lane >> 3;
    const int sblk = (lane & 7) ^ srow;

    f32x4 acc[RB][4];
#pragma unroll
    for (int i = 0; i < RB; ++i)
#pragma unroll
        for (int j = 0; j < 4; ++j) acc[i][j] = (f32x4){0.f, 0.f, 0.f, 0.f};

    for (int kt = 0; kt < 12; ++kt) {
        __syncthreads();
#pragma unroll
        for (int i = 0; i < RB; ++i) {
            const int row = i * 32 + w * 8 + srow;
            GLOAD_LDS16(A + (size_t)(row0 + row) * lda + kt * 64 + sblk * 8,
                        ldsA + i * 4096 + w * 1024);
        }
#pragma unroll
        for (int i = 0; i < 4; ++i) {
            const int row = i * 32 + w * 8 + srow;
            GLOAD_LDS16(Bt + (size_t)(col0 + row) * D_MODEL + kt * 64 + sblk * 8,
                        ldsB + i * 4096 + w * 1024);
        }
        __syncthreads();

        bf16x8 af[RB][2], bfr[4][2];
#pragma unroll
        for (int rb = 0; rb < RB; ++rb) {
            const int r = wr * (BM / 2) + rb * 16 + l15;
#pragma unroll
            for (int c = 0; c < 2; ++c)
                af[rb][c] = *(const bf16x8*)(ldsA + r * 128 + (((c * 4 + l4) ^ (r & 7)) << 4));
        }
#pragma unroll
        for (int cb = 0; cb < 4; ++cb) {
            const int r = wc * 64 + cb * 16 + l15;
#pragma unroll
            for (int c = 0; c < 2; ++c)
                bfr[cb][c] = *(const bf16x8*)(ldsB + r * 128 + (((c * 4 + l4) ^ (r & 7)) << 4));
        }
        __builtin_amdgcn_s_setprio(1);
#pragma unroll
        for (int rb = 0; rb < RB; ++rb)
#pragma unroll
            for (int cb = 0; cb < 4; ++cb) {
                acc[rb][cb] = __builtin_amdgcn_mfma_f32_16x16x32_bf16(
                    af[rb][0], bfr[cb][0], acc[rb][cb], 0, 0, 0);
                acc[rb][cb] = __builtin_amdgcn_mfma_f32_16x16x32_bf16(
                    af[rb][1], bfr[cb][1], acc[rb][cb], 0, 0, 0);
            }
        __builtin_amdgcn_s_setprio(0);
    }

#pragma unroll
    for (int cb = 0; cb < 4; ++cb) {
        const int col = col0 + wc * 64 + cb * 16 + l15;
        const float bv = bias[col];
        if (out_mode == 2) {
            const int h  = col >> 6, dh = col & 63;
#pragma unroll
            for (int rb = 0; rb < RB; ++rb) {
                const int row = row0 + wr * (BM / 2) + rb * 16 + 4 * l4;
                const int b   = row >> 11, s0 = row & 2047;
                short4v s4;
                s4[0] = f2bf(acc[rb][cb][0] + bv);
                s4[1] = f2bf(acc[rb][cb][1] + bv);
                s4[2] = f2bf(acc[rb][cb][2] + bv);
                s4[3] = f2bf(acc[rb][cb][3] + bv);
                *(short4v*)((short*)C + ((size_t)((b * 12 + h) * 64 + dh)) * S_LEN + s0) = s4;
            }
        } else {
#pragma unroll
            for (int rb = 0; rb < RB; ++rb)
#pragma unroll
                for (int r = 0; r < 4; ++r) {
                    const int row = row0 + wr * (BM / 2) + rb * 16 + 4 * l4 + r;
                    const float val = acc[rb][cb][r] + bv;
                    if (out_mode == 1) ((short*)C)[(size_t)row * ldc + col] = f2bf(val);
                    else               ((float*)C)[(size_t)row * ldc + col] = val;
                }
        }
    }
}

// qkv: BM=64 -> grid (6,64,3) = 1152 blocks (4.5/CU)
__global__ __launch_bounds__(256) void qkv_gemm_kernel(
    const short* __restrict__ xb, const short* __restrict__ wt,
    const float* __restrict__ bq, const float* __restrict__ bk,
    const float* __restrict__ bv, short* __restrict__ qkv)
{
    const int which = blockIdx.z;
    const float* bias = (which == 0) ? bq : (which == 1) ? bk : bv;
    gemm_bt_body<64>(xb + which * D_MODEL, 3 * D_MODEL,
                     wt + (size_t)which * D_MODEL * D_MODEL, bias,
                     qkv + (size_t)which * BATCH * S_LEN * D_MODEL, D_MODEL,
                     (which == 2) ? 2 : 1);
}

// proj: BM=64 -> grid (6,64)=384 blocks
__global__ __launch_bounds__(256) void proj_gemm_kernel(
    const short* __restrict__ att, const short* __restrict__ wct,
    const float* __restrict__ bc, float* __restrict__ out)
{
    gemm_bt_body<64>(att, D_MODEL, wct, bc, out, D_MODEL, 0);
}

// ---------------------------------------------------------------------------
// Flash attention v8 (R10/R12/R16 — best configuration). Grid (16,12,2),
// 512 thr = 8 waves: 2 KV-groups x 4 q-waves, K/V double-buffered,
// Vt staged via global_load_lds, in-register softmax (exp2 space),
// defer-max, in-LDS 2-way flash-decode merge + direct store.
// bh>=16 flip pairs long/short causal blocks on co-resident CUs.
// ---------------------------------------------------------------------------
__global__ __launch_bounds__(512, 4) void attn_mfma_kernel(
    const short* __restrict__ q, const short* __restrict__ k,
    const short* __restrict__ vt, short* __restrict__ o)
{
    __shared__ __align__(16) char bufK[2][2][8192];   // [group][dbuf]
    __shared__ __align__(16) char bufV[2][2][8192];
    __shared__ float mlx[2][128];

    const int t    = threadIdx.x;
    const int lane = t & 63;
    const int w    = t >> 6;
    const int g    = w >> 2;
    const int w4   = w & 3;
    const int l31  = lane & 31;
    const int hi   = lane >> 5;
    const int r7   = l31 & 7;

    const int h  = blockIdx.y;
    const int b  = blockIdx.z;
    const int bh = h + 12 * b;
    const int qt = (bh >= 16) ? (15 - (int)blockIdx.x) : (int)blockIdx.x;
    const int nt = qt + 1;

    const size_t base   = (size_t)b * (S_LEN * D_MODEL) + h * DH;
    const size_t vtbase = (size_t)bh * DH * S_LEN;
    const int q0 = qt * 128 + w4 * 32;

    // ---- Q B-frags; scale = 0.125*log2e folded in (exp2-space softmax) ----
    bf16x8 qf[4];
    {
        const float qscale = 0.18033688f;
        const short* qp = q + base + (size_t)(q0 + l31) * D_MODEL + 8 * hi;
#pragma unroll
        for (int dc = 0; dc < 4; ++dc) {
            bf16x8 r = *(const bf16x8*)(qp + 16 * dc);
#pragma unroll
            for (int j = 0; j < 8; ++j) r[j] = f2bf(bf2f(r[j]) * qscale);
            qf[dc] = r;
        }
    }

    f32x16 oT[2];
    oT[0] = (f32x16)(0.f); oT[1] = (f32x16)(0.f);
    float mrun = -1e30f, lrun = 0.f;

    const int srow = lane >> 3;
    const int sblk = (lane & 7) ^ srow;

    // ---- prologue: stage this group's tile 0 ----
    {
        const int tk0 = g * nt;
#pragma unroll
        for (int i = 0; i < 2; ++i) {
            const int row = i * 32 + w4 * 8 + srow;
            GLOAD_LDS16(k  + base   + (size_t)(tk0 * 64 + row) * D_MODEL + sblk * 8,
                        bufK[g][0] + i * 4096 + w4 * 1024);
            GLOAD_LDS16(vt + vtbase + (size_t)row * S_LEN + tk0 * 64 + sblk * 8,
                        bufV[g][0] + i * 4096 + w4 * 1024);
        }
        __syncthreads();
    }

    for (int i = 0; i < nt; ++i) {
        const int cur = i & 1, nxt = cur ^ 1;
        const bool have_next = (i + 1 < nt);
        const int tk = g * nt + i;

        // ---- issue next-tile loads first (hide HBM under compute) ----
        if (have_next) {
            const int tkn = tk + 1;
#pragma unroll
            for (int j = 0; j < 2; ++j) {
                const int row = j * 32 + w4 * 8 + srow;
                GLOAD_LDS16(k  + base   + (size_t)(tkn * 64 + row) * D_MODEL + sblk * 8,
                            bufK[g][nxt] + (size_t)(j * 4096 + w4 * 1024));
                GLOAD_LDS16(vt + vtbase + (size_t)row * S_LEN + tkn * 64 + sblk * 8,
                            bufV[g][nxt] + (size_t)(j * 4096 + w4 * 1024));
            }
        }

        // ---- compute tile tk (wave-uniform causal skip) ----
        if (tk * 64 <= q0 + 31) {
            f32x16 cS[2];
            __builtin_amdgcn_s_setprio(1);
#pragma unroll
            for (int s = 0; s < 2; ++s) {
                f32x16 acc = (f32x16)(0.f);
#pragma unroll
                for (int dc = 0; dc < 4; ++dc) {
                    const int row = 32 * s + l31;
                    const bf16x8 kf = *(const bf16x8*)(
                        bufK[g][cur] + row * 128 + (((unsigned)(32 * dc + 16 * hi)) ^ ((unsigned)r7 << 4)));
                    acc = __builtin_amdgcn_mfma_f32_32x32x16_bf16(kf, qf[dc], acc, 0, 0, 0);
                }
                cS[s] = acc;
            }
            __builtin_amdgcn_s_setprio(0);

            if (tk * 64 + 63 > q0) {   // boundary tiles: causal mask
                const int qg = q0 + l31;
#pragma unroll
                for (int s = 0; s < 2; ++s)
#pragma unroll
                    for (int rg = 0; rg < 16; ++rg) {
                        const int key = tk * 64 + 32 * s + (rg & 3) + 8 * (rg >> 2) + 4 * hi;
                        if (key > qg) cS[s][rg] = -1e30f;
                    }
            }

            // online softmax in exp2 space, defer-max (THR = 8*log2e = 11.52)
            float pmax = -1e30f;
#pragma unroll
            for (int s = 0; s < 2; ++s)
#pragma unroll
                for (int rg = 0; rg < 16; ++rg) pmax = fmaxf(pmax, cS[s][rg]);
            pmax = fmaxf(pmax, __shfl_xor(pmax, 32));

            if (!__all(pmax - mrun <= 11.52f)) {
                const float mnew = fmaxf(mrun, pmax);
                const float corr = exp2_fast(mrun - mnew);
                lrun *= corr;
#pragma unroll
                for (int d0 = 0; d0 < 2; ++d0)
#pragma unroll
                    for (int rg = 0; rg < 16; ++rg) oT[d0][rg] *= corr;
                mrun = mnew;
            }
            float psum = 0.f;
#pragma unroll
            for (int s = 0; s < 2; ++s)
#pragma unroll
                for (int rg = 0; rg < 16; ++rg) {
                    const float e = exp2_fast(cS[s][rg] - mrun);
                    cS[s][rg] = e; psum += e;
                }
            psum += __shfl_xor(psum, 32);
            lrun += psum;

            // P -> bf16 B-frags in-register
            bf16x8 pfrag[4];
#pragma unroll
            for (int s = 0; s < 2; ++s)
#pragma unroll
                for (int tt = 0; tt < 2; ++tt) {
                    unsigned a0 = cvt_pk_bf16(cS[s][8 * tt + 0], cS[s][8 * tt + 1]);
                    unsigned a1 = cvt_pk_bf16(cS[s][8 * tt + 2], cS[s][8 * tt + 3]);
                    unsigned b0 = cvt_pk_bf16(cS[s][8 * tt + 4], cS[s][8 * tt + 5]);
                    unsigned b1 = cvt_pk_bf16(cS[s][8 * tt + 6], cS[s][8 * tt + 7]);
                    perm32swap(a0, b0);
                    perm32swap(a1, b1);
                    union { unsigned u[4]; bf16x8 v8; } pk;
                    pk.u[0] = a0; pk.u[1] = a1; pk.u[2] = b0; pk.u[3] = b1;
                    pfrag[2 * s + tt] = pk.v8;
                }

            // O^T += Vt . P
            __builtin_amdgcn_s_setprio(1);
#pragma unroll
            for (int d0 = 0; d0 < 2; ++d0) {
                f32x16 acc = oT[d0];
#pragma unroll
                for (int c = 0; c < 4; ++c) {
                    const int row = 32 * d0 + l31;
                    const bf16x8 vf = *(const bf16x8*)(
                        bufV[g][cur] + row * 128 + (((unsigned)(32 * c + 16 * hi)) ^ ((unsigned)r7 << 4)));
                    acc = __builtin_amdgcn_mfma_f32_32x32x16_bf16(vf, pfrag[c], acc, 0, 0, 0);
                }
                oT[d0] = acc;
            }
            __builtin_amdgcn_s_setprio(0);
        }
        __syncthreads();
    }

    // ---- group 1 publishes unnormalized partials into dead bufK LDS ----
    if (g == 1) {
        float* ex = (float*)(&bufK[0][0][0]) + w4 * 2048;
#pragma unroll
        for (int d0 = 0; d0 < 2; ++d0)
#pragma unroll
            for (int rg = 0; rg < 16; ++rg)
                ex[(d0 * 16 + rg) * 64 + lane] = oT[d0][rg];
        if (hi == 0) {
            mlx[0][w4 * 32 + l31] = mrun;
            mlx[1][w4 * 32 + l31] = lrun;
        }
    }
    __syncthreads();

    // ---- group 0: flash-decode combine + DIRECT global store ----
    if (g == 0) {
        const int row = w4 * 32 + l31;
        const float m1  = mlx[0][row];
        const float l1v = mlx[1][row];
        const float M   = fmaxf(mrun, m1);
        const float a0  = exp2_fast(mrun - M);
        const float a1  = exp2_fast(m1 - M);
        const float inv = 1.f / (a0 * lrun + a1 * l1v);
        const float c0  = a0 * inv;
        const float c1  = a1 * inv;
        const float* ex = (const float*)(&bufK[0][0][0]) + w4 * 2048;

        short* orow = o + base + (size_t)(qt * 128 + row) * D_MODEL;
#pragma unroll
        for (int d0 = 0; d0 < 2; ++d0)
#pragma unroll
            for (int gg = 0; gg < 4; ++gg) {
                short4v s4;
#pragma unroll
                for (int j = 0; j < 4; ++j) {
                    const int rg = 4 * gg + j;
                    const float val = c0 * oT[d0][rg] + c1 * ex[(d0 * 16 + rg) * 64 + lane];
                    s4[j] = f2bf(val);
                }
                *(short4v*)(orow + 32 * d0 + 8 * gg + 4 * hi) = s4;
            }
    }
}

extern "C" void kernel_launch(void* const* d_in, const int* in_sizes, int n_in,
                              void* d_out, int out_size, void* d_ws, size_t ws_size,
                              hipStream_t stream)
{
    const float* x  = (const float*)d_in[0];
    // d_in[1] = mask: exact causal triu -> analytic, not read
    const float* wq = (const float*)d_in[2];
    const float* bq = (const float*)d_in[3];
    const float* wk = (const float*)d_in[4];
    const float* bk = (const float*)d_in[5];
    const float* wv = (const float*)d_in[6];
    const float* bv = (const float*)d_in[7];
    const float* wc = (const float*)d_in[8];
    const float* bc = (const float*)d_in[9];
    float* out = (float*)d_out;

    const size_t nx  = (size_t)BATCH * S_LEN * 3 * D_MODEL;
    const size_t nw  = (size_t)D_MODEL * D_MODEL;
    const size_t nqv = (size_t)BATCH * S_LEN * D_MODEL;

    short* xb  = (short*)d_ws;
    short* wt  = xb + nx;
    short* qkv = wt + 4 * nw;        // q | k | Vt (Vt transposed per head)
    short* att = qkv + 3 * nqv;

    dim3 blk(256);
    convert_xw_kernel<<<dim3(4608 + 576), blk, 0, stream>>>(x, xb, wq, wk, wv, wc, wt);
    qkv_gemm_kernel  <<<dim3(6, 64, 3), blk, 0, stream>>>(xb, wt, bq, bk, bv, qkv);
    attn_mfma_kernel <<<dim3(16, NH, BATCH), dim3(512), 0, stream>>>(
        qkv, qkv + nqv, qkv + 2 * nqv, att);
    proj_gemm_kernel <<<dim3(6, 64), blk, 0, stream>>>(att, wt + 3 * nw, bc, out);
}